// Round 1
// baseline (115.025 us; speedup 1.0000x reference)
//
#include <hip/hip_runtime.h>

#define NR_CLASSES 8

__global__ void WordMajority_kernel(const int* __restrict__ x,
                                    const int* __restrict__ y,
                                    const float* __restrict__ mc,
                                    float* __restrict__ logits,   // [n*8]
                                    float* __restrict__ y_out,    // [n]
                                    float* __restrict__ pred_out, // [n]
                                    int n) {
    int i = blockIdx.x * blockDim.x + threadIdx.x;
    const int stride = gridDim.x * blockDim.x;
    for (; i < n; i += stride) {
        const int xi = x[i];
        const float4* row = reinterpret_cast<const float4*>(mc + (size_t)xi * NR_CLASSES);
        float4 a = row[0];
        float4 b = row[1];
        float vals[NR_CLASSES] = {a.x, a.y, a.z, a.w, b.x, b.y, b.z, b.w};

        // first-max-wins argmax (matches jnp.argmax tie-breaking)
        int best = 0;
        float bv = vals[0];
#pragma unroll
        for (int c = 1; c < NR_CLASSES; ++c) {
            if (vals[c] > bv) { bv = vals[c]; best = c; }
        }

        float o[NR_CLASSES];
#pragma unroll
        for (int c = 0; c < NR_CLASSES; ++c) o[c] = (c == best) ? 1.0f : 0.0f;

        float4* lo = reinterpret_cast<float4*>(logits + (size_t)i * NR_CLASSES);
        lo[0] = make_float4(o[0], o[1], o[2], o[3]);
        lo[1] = make_float4(o[4], o[5], o[6], o[7]);

        y_out[i]    = (float)y[i];
        pred_out[i] = (float)best;
    }
}

extern "C" void kernel_launch(void* const* d_in, const int* in_sizes, int n_in,
                              void* d_out, int out_size, void* d_ws, size_t ws_size,
                              hipStream_t stream) {
    const int*   x  = (const int*)d_in[0];          // [256*8192] int32
    const int*   y  = (const int*)d_in[1];          // [256*8192] int32
    const float* mc = (const float*)d_in[2];        // [50257*8]  float32

    const int n = in_sizes[0];                      // 2,097,152 tokens

    float* out      = (float*)d_out;
    float* logits   = out;                          // n*8 floats
    float* y_out    = out + (size_t)n * NR_CLASSES; // n floats
    float* pred_out = y_out + n;                    // n floats

    const int block = 256;
    int grid = (n + block - 1) / block;
    if (grid > 2048) grid = 2048;                   // grid-stride the rest

    WordMajority_kernel<<<grid, block, 0, stream>>>(x, y, mc, logits, y_out, pred_out, n);
}

// Round 2
// 114.193 us; speedup vs baseline: 1.0073x; 1.0073x over previous
//
#include <hip/hip_runtime.h>

#define NR_CLASSES 8

typedef float f32x4 __attribute__((ext_vector_type(4)));

__global__ __launch_bounds__(256) void WordMajority_kernel(
    const int* __restrict__ x,
    const int* __restrict__ y,
    const float* __restrict__ mc,
    float* __restrict__ logits,   // [n*8]
    float* __restrict__ y_out,    // [n]
    float* __restrict__ pred_out, // [n]
    int n) {
    const int i = blockIdx.x * blockDim.x + threadIdx.x;   // one token per thread
    if (i >= n) return;                                    // n % 64 == 0: waves uniform
    const int lane = threadIdx.x & 63;

    // streaming inputs: non-temporal so they don't evict the gather table from L2
    const int xi = __builtin_nontemporal_load(x + i);
    const int yi = __builtin_nontemporal_load(y + i);

    // gather the 32B table row (normal load: we WANT this cached in L2)
    const f32x4* row = reinterpret_cast<const f32x4*>(mc + (size_t)xi * NR_CLASSES);
    f32x4 a = row[0];
    f32x4 b = row[1];
    float vals[NR_CLASSES] = {a.x, a.y, a.z, a.w, b.x, b.y, b.z, b.w};

    // first-max-wins argmax (matches jnp.argmax tie-breaking)
    int best = 0;
    float bv = vals[0];
#pragma unroll
    for (int c = 1; c < NR_CLASSES; ++c) {
        if (vals[c] > bv) { bv = vals[c]; best = c; }
    }

    // Perfectly coalesced one-hot stores:
    // wave covers tokens [wbase, wbase+64) -> logits f32x4 slots [2*wbase, 2*wbase+128).
    // store s: lane writes slot s*64+lane; that slot belongs to token (s*64+lane)>>1,
    // half h = slot&1. Fetch that token's argmax via shuffle.
    const int wbase = i - lane;
    f32x4* lbase = reinterpret_cast<f32x4*>(logits) + (size_t)2 * wbase;

#pragma unroll
    for (int s = 0; s < 2; ++s) {
        const int slot = s * 64 + lane;
        const int srcLane = slot >> 1;
        const int h = slot & 1;
        const int b_tok = __shfl(best, srcLane, 64);
        f32x4 v;
        v.x = (b_tok == h * 4 + 0) ? 1.0f : 0.0f;
        v.y = (b_tok == h * 4 + 1) ? 1.0f : 0.0f;
        v.z = (b_tok == h * 4 + 2) ? 1.0f : 0.0f;
        v.w = (b_tok == h * 4 + 3) ? 1.0f : 0.0f;
        __builtin_nontemporal_store(v, lbase + slot);
    }

    __builtin_nontemporal_store((float)yi, y_out + i);
    __builtin_nontemporal_store((float)best, pred_out + i);
}

extern "C" void kernel_launch(void* const* d_in, const int* in_sizes, int n_in,
                              void* d_out, int out_size, void* d_ws, size_t ws_size,
                              hipStream_t stream) {
    const int*   x  = (const int*)d_in[0];          // [256*8192] int32
    const int*   y  = (const int*)d_in[1];          // [256*8192] int32
    const float* mc = (const float*)d_in[2];        // [50257*8]  float32

    const int n = in_sizes[0];                      // 2,097,152 tokens

    float* out      = (float*)d_out;
    float* logits   = out;                          // n*8 floats
    float* y_out    = out + (size_t)n * NR_CLASSES; // n floats
    float* pred_out = y_out + n;                    // n floats

    const int block = 256;
    const int grid = (n + block - 1) / block;       // exact: 8192 blocks

    WordMajority_kernel<<<grid, block, 0, stream>>>(x, y, mc, logits, y_out, pred_out, n);
}